// Round 23
// baseline (268.819 us; speedup 1.0000x reference)
//
#include <hip/hip_runtime.h>

// ---------------- constants ----------------
#define BB 4
#define TT 4096
#define DD 256
#define KQ 32
#define TOPK 4
#define NV 8
#define NL 4
#define MROWS (BB*TT)   // 16384
#define NSC 8           // s-chunk blocks in sim_scan
#define SSPAN 512       // s-rows per sim_scan block
#define NCAND (NSC*16)  // 128 candidates per row

typedef __attribute__((ext_vector_type(8))) __bf16 bf16x8;
typedef __attribute__((ext_vector_type(4))) float  f32x4;

__device__ __forceinline__ unsigned short f2bf(float f) {
  union { float f; unsigned u; } un; un.f = f;
  unsigned r = un.u + 0x7fffu + ((un.u >> 16) & 1u);
  return (unsigned short)(r >> 16);
}
__device__ __forceinline__ float b2f(unsigned short s) {
  union { unsigned u; float f; } un; un.u = ((unsigned)s) << 16;
  return un.f;
}
// async global->LDS 16B: dest is wave-uniform base (+lane*16 by HW), src per-lane
__device__ __forceinline__ void gload16(const unsigned short* g, unsigned short* l) {
  __builtin_amdgcn_global_load_lds((const __attribute__((address_space(1))) void*)(g),
                                   (__attribute__((address_space(3))) void*)(l), 16, 0, 0);
}

// keep top-4 (desc) with first-seen-wins on ties
__device__ __forceinline__ void ins4(float val, int s, float v[4], int id[4]) {
  if (val <= v[3]) return;
  v[3] = val; id[3] = s;
  #pragma unroll
  for (int j = 3; j > 0; --j) {
    if (v[j] > v[j-1]) {
      float tv = v[j]; v[j] = v[j-1]; v[j-1] = tv;
      int   ti = id[j]; id[j] = id[j-1]; id[j-1] = ti;
    }
  }
}

// ---------------- weight prep: transpose + bf16 convert ----------------
__global__ __launch_bounds__(256) void prep_weights(
    const float* __restrict__ W1f, const float* __restrict__ W2f,
    const float* __restrict__ opW1, const float* __restrict__ opW2,
    const float* __restrict__ Whh,
    unsigned short* __restrict__ W1ft, unsigned short* __restrict__ W2ft,
    unsigned short* __restrict__ opW1t, unsigned short* __restrict__ opW2t,
    unsigned int* __restrict__ Whhp) {
  int idx = blockIdx.x * 256 + threadIdx.x;
  if (idx < 131072) { int n = idx >> 8, d = idx & 255; W1ft[idx] = f2bf(W1f[d*512 + n]); return; }
  idx -= 131072;
  if (idx < 131072) { int n = idx >> 9, d = idx & 511; W2ft[idx] = f2bf(W2f[d*256 + n]); return; }
  idx -= 131072;
  if (idx < 524288) { int np = idx >> 8, d = idx & 255; int v = np >> 8, e = np & 255;
                      opW1t[idx] = f2bf(opW1[v*65536 + d*256 + e]); return; }
  idx -= 524288;
  if (idx < 524288) { int n = idx >> 11, kp = idx & 2047; int v = kp >> 8, k2 = kp & 255;
                      opW2t[idx] = f2bf(opW2[v*65536 + k2*256 + n]); return; }
  idx -= 524288;
  if (idx < 98304) {
    int dp = idx / 768, j = idx - dp*768;
    unsigned lo = f2bf(Whh[j*256 + 2*dp]);
    unsigned hi = f2bf(Whh[j*256 + 2*dp + 1]);
    Whhp[idx] = lo | (hi << 16);
  }
}

// ---------------- q/k projection (fp32 + bf16 copies) ----------------
__global__ __launch_bounds__(256) void qk_proj(
    const float* __restrict__ x, const float* __restrict__ Wq, const float* __restrict__ bq,
    const float* __restrict__ Wk, const float* __restrict__ bk,
    float* __restrict__ q, float* __restrict__ kk,
    unsigned short* __restrict__ qbf, unsigned short* __restrict__ kbf) {
  __shared__ float xs[1024];
  int tid = threadIdx.x;
  *(float4*)&xs[tid*4] = *(const float4*)&x[(size_t)blockIdx.x*1024 + tid*4];
  __syncthreads();
  int row = blockIdx.x*4 + (tid >> 6);
  int j = tid & 63;
  int jj = j & 31;
  const float* W = (j < 32) ? Wq : Wk;
  const float* xr = &xs[(tid >> 6) * 256];
  float acc = 0.f;
  #pragma unroll 8
  for (int d = 0; d < 256; ++d) acc += xr[d] * W[d*32 + jj];
  acc += (j < 32) ? bq[jj] : bk[jj];
  float* out = (j < 32) ? q : kk;
  unsigned short* outb = (j < 32) ? qbf : kbf;
  out[(size_t)row*32 + jj] = acc;
  outb[(size_t)row*32 + jj] = f2bf(acc);
}

// ---------------- sim scan via MFMA (per-lane top-4 + values) ----------------
__global__ __launch_bounds__(256) void sim_scan(
    const unsigned short* __restrict__ qbf, const unsigned short* __restrict__ kbf,
    const float* __restrict__ mask, int* __restrict__ candi, float* __restrict__ candvv) {
  int b = blockIdx.z, sc = blockIdx.y;
  int q0 = blockIdx.x * 64;
  int tid = threadIdx.x;
  int w = tid >> 6, lane = tid & 63;
  int l15 = lane & 15, lhi = lane >> 4;

  __shared__ unsigned short kfr[SSPAN*32];  // 32KB, fragment-ordered
  __shared__ float ms[SSPAN];
  __shared__ int mflag;

  int qrow = q0 + w*16 + l15;
  bf16x8 qf = *(const bf16x8*)&qbf[((size_t)b*TT + qrow)*32 + lhi*8];
  float mrow = mask[b*TT + qrow];

  float vtop[4]; int itop[4];
  #pragma unroll
  for (int r = 0; r < 4; ++r) { vtop[r] = -__builtin_inff(); itop[r] = 0; }

  int s0 = sc * SSPAN;
  if (tid == 0) mflag = 0;
  __syncthreads();
  int anyzero = 0;
  #pragma unroll
  for (int rr = 0; rr < 2; ++rr) {
    int s = rr*256 + tid;
    const unsigned short* src = &kbf[((size_t)b*TT + s0 + s)*32];
    uint4 d0 = *(const uint4*)(src);
    uint4 d1 = *(const uint4*)(src + 8);
    uint4 d2 = *(const uint4*)(src + 16);
    uint4 d3 = *(const uint4*)(src + 24);
    int fb = (s >> 4)*512 + (s & 15)*8;
    *(uint4*)&kfr[fb +   0] = d0;
    *(uint4*)&kfr[fb + 128] = d1;
    *(uint4*)&kfr[fb + 256] = d2;
    *(uint4*)&kfr[fb + 384] = d3;
    float mv = mask[b*TT + s0 + s];
    ms[s] = mv;
    if (mv == 0.f) anyzero = 1;
  }
  if (anyzero) mflag = 1;
  __syncthreads();
  bool useMask = (mflag != 0) || (mrow == 0.f);
  f32x4 z = {0.f, 0.f, 0.f, 0.f};
  for (int sf = 0; sf < SSPAN/16; sf += 2) {
    bf16x8 a0 = *(const bf16x8*)&kfr[(sf+0)*512 + lane*8];
    bf16x8 a1 = *(const bf16x8*)&kfr[(sf+1)*512 + lane*8];
    f32x4 c0 = __builtin_amdgcn_mfma_f32_16x16x32_bf16(a0, qf, z, 0, 0, 0);
    f32x4 c1 = __builtin_amdgcn_mfma_f32_16x16x32_bf16(a1, qf, z, 0, 0, 0);
    int sb0 = s0 + (sf+0)*16 + lhi*4;
    int sb1 = s0 + (sf+1)*16 + lhi*4;
    #pragma unroll
    for (int r = 0; r < 4; ++r) {
      float v0 = c0[r], v1 = c1[r];
      if (useMask) {
        if (mrow * ms[(sf+0)*16 + lhi*4 + r] == 0.f) v0 = -1e9f;
        if (mrow * ms[(sf+1)*16 + lhi*4 + r] == 0.f) v1 = -1e9f;
      }
      ins4(v0, sb0 + r, vtop, itop);
      ins4(v1, sb1 + r, vtop, itop);
    }
  }
  size_t base = ((size_t)(b*TT + qrow))*NCAND + sc*16 + lhi*4;
  #pragma unroll
  for (int r = 0; r < 4; ++r) { candi[base + r] = itop[r]; candvv[base + r] = vtop[r]; }
}

// ---------------- preselect top-8 by bf16 value + exact fp32 rank of 8 ----------------
__global__ __launch_bounds__(256) void refine8(
    const int* __restrict__ candi, const float* __restrict__ candv,
    const float* __restrict__ q, const float* __restrict__ kk,
    const float* __restrict__ mask, int* __restrict__ sel) {
  int tid = threadIdx.x;
  int g = tid >> 5, j = tid & 31;
  int row = blockIdx.x*8 + g;
  int b = row >> 12;
  float v[4]; int id[4];
  const float* cvp = &candv[(size_t)row*NCAND];
  const int*   cip = &candi[(size_t)row*NCAND];
  #pragma unroll
  for (int k2 = 0; k2 < 4; ++k2) { v[k2] = cvp[j + k2*32]; id[k2] = cip[j + k2*32]; }
  int c8[8];
  #pragma unroll
  for (int r = 0; r < 8; ++r) {
    float bv = v[0]; int bi = id[0];
    #pragma unroll
    for (int k2 = 1; k2 < 4; ++k2)
      if (v[k2] > bv || (v[k2] == bv && id[k2] < bi)) { bv = v[k2]; bi = id[k2]; }
    #pragma unroll
    for (int o = 16; o > 0; o >>= 1) {
      float ov = __shfl_xor(bv, o, 32);
      int   oi = __shfl_xor(bi, o, 32);
      if (ov > bv || (ov == bv && oi < bi)) { bv = ov; bi = oi; }
    }
    c8[r] = bi;
    #pragma unroll
    for (int k2 = 0; k2 < 4; ++k2) if (id[k2] == bi) v[k2] = -__builtin_inff();
  }
  // exact fp32 dots
  int ca = c8[j >> 2];
  int seg = (j & 3) * 8;
  const float* kp = &kk[((size_t)(b << 12) + ca)*32 + seg];
  const float* qp = &q[(size_t)row*32 + seg];
  float pd = 0.f;
  #pragma unroll
  for (int t = 0; t < 8; t += 4) {
    float4 kv = *(const float4*)&kp[t];
    float4 qv = *(const float4*)&qp[t];
    pd += kv.x*qv.x + kv.y*qv.y + kv.z*qv.z + kv.w*qv.w;
  }
  pd += __shfl_xor(pd, 1, 32);
  pd += __shfl_xor(pd, 2, 32);
  if (mask[row] * mask[(b << 12) + ca] == 0.f) pd = -1e9f;
  float dv[8];
  #pragma unroll
  for (int c = 0; c < 8; ++c) dv[c] = __shfl(pd, c*4, 32);
  if (j == 0) {
    int s0 = -1, s1 = -1, s2 = -1, s3 = -1;
    int4 o4;
    #pragma unroll
    for (int r = 0; r < 4; ++r) {
      float bv = -__builtin_inff(); int bi = 0x7fffffff;
      #pragma unroll
      for (int c = 0; c < 8; ++c) {
        int ii = c8[c]; float vv = dv[c];
        if (ii == s0 || ii == s1 || ii == s2 || ii == s3) continue;
        if (vv > bv || (vv == bv && ii < bi)) { bv = vv; bi = ii; }
      }
      if (r == 0) { o4.x = bi; s0 = bi; }
      else if (r == 1) { o4.y = bi; s1 = bi; }
      else if (r == 2) { o4.z = bi; s2 = bi; }
      else { o4.w = bi; s3 = bi; }
    }
    *(int4*)&sel[(size_t)row*4] = o4;
  }
}

// ---------------- gather + routed_mean (pure streaming) ----------------
__global__ __launch_bounds__(256) void gather_mean(
    const int* __restrict__ sel, const float* __restrict__ x,
    unsigned short* __restrict__ rmb) {
  int tid = threadIdx.x;
  int row = blockIdx.x*4 + (tid >> 6);
  int lane = tid & 63;
  int b = row >> 12;
  int4 s = *(const int4*)&sel[(size_t)row*4];
  const float* xb = &x[(size_t)b*TT*DD];
  float4 a  = *(const float4*)&xb[(size_t)s.x*DD + lane*4];
  float4 bb = *(const float4*)&xb[(size_t)s.y*DD + lane*4];
  float4 cc = *(const float4*)&xb[(size_t)s.z*DD + lane*4];
  float4 e  = *(const float4*)&xb[(size_t)s.w*DD + lane*4];
  ushort4 o;
  o.x = f2bf((a.x + bb.x + cc.x + e.x)*0.25f);
  o.y = f2bf((a.y + bb.y + cc.y + e.y)*0.25f);
  o.z = f2bf((a.z + bb.z + cc.z + e.z)*0.25f);
  o.w = f2bf((a.w + bb.w + cc.w + e.w)*0.25f);
  *(ushort4*)&rmb[(size_t)row*DD + lane*4] = o;
}

// ---------------- bf16 MFMA GEMM, 64x128 tile (long-K gemm<3>), gload_lds staging ----------------
__global__ __launch_bounds__(256) void gemm64_bf16(
    const unsigned short* __restrict__ A, const unsigned short* __restrict__ Bt,
    int Ndim, int Kdim,
    const float* __restrict__ auxf, unsigned short* __restrict__ outB) {
  __shared__ unsigned short SMEM[64*192 + 64];  // As 4096 + Bs 8192 staging; CT 64x132
  unsigned short* As = SMEM;
  unsigned short* Bs = SMEM + 64*64;
  int tid = threadIdx.x;
  int lane = tid & 63, wn = tid >> 6;
  int l16 = lane & 15, lhi = lane >> 4;
  int m0 = blockIdx.x * 64, n0 = blockIdx.y * 128;
  f32x4 acc[4][2] = {};
  for (int kt = 0; kt < Kdim; kt += 64) {
    __syncthreads();
    #pragma unroll
    for (int i = 0; i < 2; ++i) {
      int L0 = i*256 + wn*64;
      int L  = L0 + lane;
      int r = L >> 3;
      int csrc = ((lane & 7) ^ (r & 7)) * 8;
      gload16(A + (size_t)(m0 + r)*Kdim + kt + csrc, &As[L0*8]);
    }
    #pragma unroll
    for (int i = 0; i < 4; ++i) {
      int L0 = i*256 + wn*64;
      int L  = L0 + lane;
      int r = L >> 3;
      int csrc = ((lane & 7) ^ (r & 7)) * 8;
      gload16(Bt + (size_t)(n0 + r)*Kdim + kt + csrc, &Bs[L0*8]);
    }
    __syncthreads();
    #pragma unroll
    for (int ks = 0; ks < 2; ++ks) {
      bf16x8 af[4], bfr[2];
      int kc = ks*4 + lhi;
      #pragma unroll
      for (int f = 0; f < 4; ++f) {
        int ra = f*16 + l16;
        af[f] = *(const bf16x8*)&As[ra*64 + ((kc ^ (ra & 7)))*8];
      }
      #pragma unroll
      for (int f = 0; f < 2; ++f) {
        int rb = wn*32 + f*16 + l16;
        bfr[f] = *(const bf16x8*)&Bs[rb*64 + ((kc ^ (rb & 7)))*8];
      }
      #pragma unroll
      for (int mf = 0; mf < 4; ++mf)
        #pragma unroll
        for (int nf = 0; nf < 2; ++nf)
          acc[mf][nf] = __builtin_amdgcn_mfma_f32_16x16x32_bf16(af[mf], bfr[nf], acc[mf][nf], 0, 0, 0);
    }
  }
  __syncthreads();   // reuse SMEM as CT[64][132]
  #pragma unroll
  for (int mf = 0; mf < 4; ++mf) {
    #pragma unroll
    for (int nf = 0; nf < 2; ++nf) {
      #pragma unroll
      for (int r = 0; r < 4; ++r) {
        int lrow = mf*16 + lhi*4 + r;
        int lcol = wn*32 + nf*16 + l16;
        float v = acc[mf][nf][r] + auxf[((m0 + lrow) >> 12)*256 + n0 + lcol];
        SMEM[lrow*132 + lcol] = f2bf(v);
      }
    }
  }
  __syncthreads();
  #pragma unroll
  for (int i = 0; i < 4; ++i) {
    int idx = i*256 + tid;
    int lrow = idx >> 4, co = (idx & 15)*8;
    *(uint4*)&outB[(size_t)(m0 + lrow)*Ndim + n0 + co] = *(const uint4*)&SMEM[lrow*132 + co];
  }
}

// ---------------- gemm64 variant for op GEMM-A: relu(acc + opb1)*w -> bf16, CT-retile ----------------
__global__ __launch_bounds__(256) void gemm64_opA(
    const unsigned short* __restrict__ A, const unsigned short* __restrict__ Bt,
    int Ndim, int Kdim,
    const float* __restrict__ bias, const float* __restrict__ wv,
    unsigned short* __restrict__ outB) {
  __shared__ unsigned short SMEM[64*192 + 64];
  unsigned short* As = SMEM;
  unsigned short* Bs = SMEM + 64*64;
  int tid = threadIdx.x;
  int lane = tid & 63, wn = tid >> 6;
  int l16 = lane & 15, lhi = lane >> 4;
  int m0 = blockIdx.x * 64, n0 = blockIdx.y * 128;
  f32x4 acc[4][2] = {};
  for (int kt = 0; kt < Kdim; kt += 64) {
    __syncthreads();
    #pragma unroll
    for (int i = 0; i < 2; ++i) {
      int L0 = i*256 + wn*64;
      int L  = L0 + lane;
      int r = L >> 3;
      int csrc = ((lane & 7) ^ (r & 7)) * 8;
      gload16(A + (size_t)(m0 + r)*Kdim + kt + csrc, &As[L0*8]);
    }
    #pragma unroll
    for (int i = 0; i < 4; ++i) {
      int L0 = i*256 + wn*64;
      int L  = L0 + lane;
      int r = L >> 3;
      int csrc = ((lane & 7) ^ (r & 7)) * 8;
      gload16(Bt + (size_t)(n0 + r)*Kdim + kt + csrc, &Bs[L0*8]);
    }
    __syncthreads();
    #pragma unroll
    for (int ks = 0; ks < 2; ++ks) {
      bf16x8 af[4], bfr[2];
      int kc = ks*4 + lhi;
      #pragma unroll
      for (int f = 0; f < 4; ++f) {
        int ra = f*16 + l16;
        af[f] = *(const bf16x8*)&As[ra*64 + ((kc ^ (ra & 7)))*8];
      }
      #pragma unroll
      for (int f = 0; f < 2; ++f) {
        int rb = wn*32 + f*16 + l16;
        bfr[f] = *(const bf16x8*)&Bs[rb*64 + ((kc ^ (rb & 7)))*8];
      }
      #pragma unroll
      for (int mf = 0; mf < 4; ++mf)
        #pragma unroll
        for (int nf = 0; nf < 2; ++nf)
          acc[mf][nf] = __builtin_amdgcn_mfma_f32_16x16x32_bf16(af[mf], bfr[nf], acc[mf][nf], 0, 0, 0);
    }
  }
  __syncthreads();   // reuse SMEM as CT[64][132]
  int bq = (m0 >> 12);                    // batch index (rows/4096)
  #pragma unroll
  for (int mf = 0; mf < 4; ++mf) {
    #pragma unroll
    for (int nf = 0; nf < 2; ++nf) {
      int col = n0 + wn*32 + nf*16 + l16;
      float bv = bias[col];
      float wvv = wv[bq*8 + (col >> 8)];
      #pragma unroll
      for (int r = 0; r < 4; ++r) {
        int lrow = mf*16 + lhi*4 + r;
        int lcol = wn*32 + nf*16 + l16;
        float v = acc[mf][nf][r] + bv;
        v = fmaxf(v, 0.0f) * wvv;
        SMEM[lrow*132 + lcol] = f2bf(v);
      }
    }
  }
  __syncthreads();
  #pragma unroll
  for (int i = 0; i < 4; ++i) {
    int idx = i*256 + tid;
    int lrow = idx >> 4, co = (idx & 15)*8;
    *(uint4*)&outB[(size_t)(m0 + lrow)*Ndim + n0 + co] = *(const uint4*)&SMEM[lrow*132 + co];
  }
}

// ---------------- gemm64 variant for FFN1: gelu(acc + bias) -> bf16, CT-retile ----------------
__global__ __launch_bounds__(256) void gemm64_gelu(
    const unsigned short* __restrict__ A, const unsigned short* __restrict__ Bt,
    int Ndim, int Kdim,
    const float* __restrict__ bias, unsigned short* __restrict__ outB) {
  __shared__ unsigned short SMEM[64*192 + 64];
  unsigned short* As = SMEM;
  unsigned short* Bs = SMEM + 64*64;
  int tid = threadIdx.x;
  int lane = tid & 63, wn = tid >> 6;
  int l16 = lane & 15, lhi = lane >> 4;
  int m0 = blockIdx.x * 64, n0 = blockIdx.y * 128;
  f32x4 acc[4][2] = {};
  for (int kt = 0; kt < Kdim; kt += 64) {
    __syncthreads();
    #pragma unroll
    for (int i = 0; i < 2; ++i) {
      int L0 = i*256 + wn*64;
      int L  = L0 + lane;
      int r = L >> 3;
      int csrc = ((lane & 7) ^ (r & 7)) * 8;
      gload16(A + (size_t)(m0 + r)*Kdim + kt + csrc, &As[L0*8]);
    }
    #pragma unroll
    for (int i = 0; i < 4; ++i) {
      int L0 = i*256 + wn*64;
      int L  = L0 + lane;
      int r = L >> 3;
      int csrc = ((lane & 7) ^ (r & 7)) * 8;
      gload16(Bt + (size_t)(n0 + r)*Kdim + kt + csrc, &Bs[L0*8]);
    }
    __syncthreads();
    #pragma unroll
    for (int ks = 0; ks < 2; ++ks) {
      bf16x8 af[4], bfr[2];
      int kc = ks*4 + lhi;
      #pragma unroll
      for (int f = 0; f < 4; ++f) {
        int ra = f*16 + l16;
        af[f] = *(const bf16x8*)&As[ra*64 + ((kc ^ (ra & 7)))*8];
      }
      #pragma unroll
      for (int f = 0; f < 2; ++f) {
        int rb = wn*32 + f*16 + l16;
        bfr[f] = *(const bf16x8*)&Bs[rb*64 + ((kc ^ (rb & 7)))*8];
      }
      #pragma unroll
      for (int mf = 0; mf < 4; ++mf)
        #pragma unroll
        for (int nf = 0; nf < 2; ++nf)
          acc[mf][nf] = __builtin_amdgcn_mfma_f32_16x16x32_bf16(af[mf], bfr[nf], acc[mf][nf], 0, 0, 0);
    }
  }
  __syncthreads();   // reuse SMEM as CT[64][132]
  #pragma unroll
  for (int mf = 0; mf < 4; ++mf) {
    #pragma unroll
    for (int nf = 0; nf < 2; ++nf) {
      int col = n0 + wn*32 + nf*16 + l16;
      float bv = bias[col];
      #pragma unroll
      for (int r = 0; r < 4; ++r) {
        int lrow = mf*16 + lhi*4 + r;
        int lcol = wn*32 + nf*16 + l16;
        float v = acc[mf][nf][r] + bv;
        v = 0.5f * v * (1.0f + erff(v * 0.70710678118654752f));
        SMEM[lrow*132 + lcol] = f2bf(v);
      }
    }
  }
  __syncthreads();
  #pragma unroll
  for (int i = 0; i < 4; ++i) {
    int idx = i*256 + tid;
    int lrow = idx >> 4, co = (idx & 15)*8;
    *(uint4*)&outB[(size_t)(m0 + lrow)*Ndim + n0 + co] = *(const uint4*)&SMEM[lrow*132 + co];
  }
}

// ---------------- gemm64 variant for FFN2: f32 preLN = acc + bias + residual ----------------
__global__ __launch_bounds__(256) void gemm64_ffn2(
    const unsigned short* __restrict__ A, const unsigned short* __restrict__ Bt,
    int Ndim, int Kdim,
    const float* __restrict__ bias, const unsigned short* __restrict__ resB,
    float* __restrict__ outF) {
  __shared__ unsigned short SMEM[64*192 + 64];
  unsigned short* As = SMEM;
  unsigned short* Bs = SMEM + 64*64;
  int tid = threadIdx.x;
  int lane = tid & 63, wn = tid >> 6;
  int l16 = lane & 15, lhi = lane >> 4;
  int m0 = blockIdx.x * 64, n0 = blockIdx.y * 128;
  f32x4 acc[4][2] = {};
  for (int kt = 0; kt < Kdim; kt += 64) {
    __syncthreads();
    #pragma unroll
    for (int i = 0; i < 2; ++i) {
      int L0 = i*256 + wn*64;
      int L  = L0 + lane;
      int r = L >> 3;
      int csrc = ((lane & 7) ^ (r & 7)) * 8;
      gload16(A + (size_t)(m0 + r)*Kdim + kt + csrc, &As[L0*8]);
    }
    #pragma unroll
    for (int i = 0; i < 4; ++i) {
      int L0 = i*256 + wn*64;
      int L  = L0 + lane;
      int r = L >> 3;
      int csrc = ((lane & 7) ^ (r & 7)) * 8;
      gload16(Bt + (size_t)(n0 + r)*Kdim + kt + csrc, &Bs[L0*8]);
    }
    __syncthreads();
    #pragma unroll
    for (int ks = 0; ks < 2; ++ks) {
      bf16x8 af[4], bfr[2];
      int kc = ks*4 + lhi;
      #pragma unroll
      for (int f = 0; f < 4; ++f) {
        int ra = f*16 + l16;
        af[f] = *(const bf16x8*)&As[ra*64 + ((kc ^ (ra & 7)))*8];
      }
      #pragma unroll
      for (int f = 0; f < 2; ++f) {
        int rb = wn*32 + f*16 + l16;
        bfr[f] = *(const bf16x8*)&Bs[rb*64 + ((kc ^ (rb & 7)))*8];
      }
      #pragma unroll
      for (int mf = 0; mf < 4; ++mf)
        #pragma unroll
        for (int nf = 0; nf < 2; ++nf)
          acc[mf][nf] = __builtin_amdgcn_mfma_f32_16x16x32_bf16(af[mf], bfr[nf], acc[mf][nf], 0, 0, 0);
    }
  }
  #pragma unroll
  for (int mf = 0; mf < 4; ++mf) {
    #pragma unroll
    for (int nf = 0; nf < 2; ++nf) {
      #pragma unroll
      for (int r = 0; r < 4; ++r) {
        int row = m0 + mf*16 + lhi*4 + r;
        int col = n0 + wn*32 + nf*16 + l16;
        float v = acc[mf][nf][r] + bias[col] + b2f(resB[(size_t)row*Ndim + col]);
        outF[(size_t)row*Ndim + col] = v;
      }
    }
  }
}

// ---------------- LayerNorm: one wave per row ----------------
__global__ __launch_bounds__(256) void ln_kernel(
    const float* __restrict__ preLN, const float* __restrict__ g,
    const float* __restrict__ bta, unsigned short* __restrict__ h) {
  int tid = threadIdx.x;
  int lane = tid & 63;
  int row = blockIdx.x*4 + (tid >> 6);
  float4 v = *(const float4*)&preLN[(size_t)row*256 + lane*4];
  float s = v.x + v.y + v.z + v.w;
  #pragma unroll
  for (int o = 32; o > 0; o >>= 1) s += __shfl_xor(s, o);
  float mu = s * (1.0f/256.0f);
  float4 d; d.x = v.x-mu; d.y = v.y-mu; d.z = v.z-mu; d.w = v.w-mu;
  float s2 = d.x*d.x + d.y*d.y + d.z*d.z + d.w*d.w;
  #pragma unroll
  for (int o = 32; o > 0; o >>= 1) s2 += __shfl_xor(s2, o);
  float rstd = rsqrtf(s2 * (1.0f/256.0f) + 1e-5f);
  float4 gv = *(const float4*)&g[lane*4];
  float4 bv = *(const float4*)&bta[lane*4];
  ushort4 o;
  o.x = f2bf(d.x*rstd*gv.x + bv.x);
  o.y = f2bf(d.y*rstd*gv.y + bv.y);
  o.z = f2bf(d.z*rstd*gv.z + bv.z);
  o.w = f2bf(d.w*rstd*gv.w + bv.w);
  *(ushort4*)&h[(size_t)row*256 + lane*4] = o;
}

// ---------------- partial column-sum of h (64-row chunks) ----------------
__global__ __launch_bounds__(256) void hsum_kernel(const unsigned short* __restrict__ h, float* __restrict__ hpart) {
  int c = blockIdx.x, b = blockIdx.y, d = threadIdx.x;
  const unsigned short* hp = &h[((size_t)(b*TT + c*64))*256 + d];
  float s = 0.f;
  #pragma unroll 8
  for (int i = 0; i < 64; ++i) s += b2f(hp[i*256]);
  hpart[(b*64 + c)*256 + d] = s;
}

// ---------------- GRU v5: 1024 threads (16 waves), one gate output per thread ----------------
__global__ __launch_bounds__(1024) void gru_kernel(
    const float* __restrict__ hpart, const unsigned int* __restrict__ Whhp,
    const float* __restrict__ b_ih, const float* __restrict__ b_hh,
    const float* __restrict__ Wp, const float* __restrict__ bp,
    const float* __restrict__ opb2, float* __restrict__ w, float* __restrict__ wb2) {
  int b = blockIdx.x, tid = threadIdx.x;
  __shared__ float hs[256];
  __shared__ float gsh[768];
  __shared__ float wps[2048];
  __shared__ float lgpart[256];
  __shared__ float lg[8];
  __shared__ float wacc[8];
  if (tid < 256) {
    float s = 0.f;
    #pragma unroll
    for (int c = 0; c < 64; ++c) s += hpart[(b*64 + c)*256 + tid];
    hs[tid] = s * (1.0f/4096.0f);
  }
  wps[tid] = Wp[tid];
  wps[1024 + tid] = Wp[1024 + tid];
  if (tid < 8) wacc[tid] = 0.f;
  __syncthreads();
  for (int l = 0; l < NL; ++l) {
    if (tid < 768) {
      float acc = 0.f;
      #pragma unroll 16
      for (int dp = 0; dp < 128; ++dp) {
        unsigned w2 = Whhp[dp*768 + tid];
        acc += b2f((unsigned short)(w2 & 0xffff))*hs[2*dp]
             + b2f((unsigned short)(w2 >> 16))*hs[2*dp + 1];
      }
      gsh[tid] = acc;
    }
    __syncthreads();
    if (tid < 256) {
      float g0 = gsh[tid]       + b_hh[tid];
      float g1 = gsh[256 + tid] + b_hh[256 + tid];
      float g2 = gsh[512 + tid] + b_hh[512 + tid];
      float r = 1.f / (1.f + expf(-(b_ih[tid] + g0)));
      float z = 1.f / (1.f + expf(-(b_ih[256 + tid] + g1)));
      float n = tanhf(b_ih[512 + tid] + r * g2);
      gsh[tid] = (1.f - z) * n + z * hs[tid];
    }
    __syncthreads();
    if (tid < 256) hs[tid] = gsh[tid];
    __syncthreads();
    if (tid < 256) {
      int dp2 = tid >> 3;
      float acc = 0.f;
      #pragma unroll
      for (int k2 = 0; k2 < 8; ++k2) acc += hs[dp2 + 32*k2] * wps[tid + 256*k2];
      lgpart[tid] = acc;
    }
    __syncthreads();
    if (tid < 8) {
      float acc = bp[tid];
      #pragma unroll
      for (int j = 0; j < 32; ++j) acc += lgpart[j*8 + tid];
      lg[tid] = acc;
    }
    __syncthreads();
    if (tid == 0) {
      float mx = lg[0];
      #pragma unroll
      for (int i = 1; i < 8; ++i) mx = fmaxf(mx, lg[i]);
      float sm = 0.f; float e[8];
      #pragma unroll
      for (int i = 0; i < 8; ++i) { e[i] = expf(lg[i] - mx); sm += e[i]; }
      #pragma unroll
      for (int i = 0; i < 8; ++i) wacc[i] += e[i] / sm;
    }
    __syncthreads();
  }
  if (tid < 8) w[b*8 + tid] = wacc[tid] * 0.25f;
  if (tid < 256) {
    float acc = 0.f;
    #pragma unroll
    for (int v = 0; v < 8; ++v) acc += (wacc[v] * 0.25f) * opb2[v*256 + tid];
    wb2[b*256 + tid] = acc;
  }
}

// ---------------- max-pool partials (64-row chunks) ----------------
__global__ __launch_bounds__(256) void maxpool_kernel(const unsigned short* __restrict__ fusedB, float* __restrict__ mpart) {
  int c = blockIdx.x, b = blockIdx.y, d = threadIdx.x;
  const unsigned short* fp = &fusedB[((size_t)(b*TT + c*64))*256 + d];
  float m = -__builtin_inff();
  #pragma unroll 8
  for (int i = 0; i < 64; ++i) m = fmaxf(m, b2f(fp[i*256]));
  mpart[(b*64 + c)*256 + d] = m;
}

// ---------------- final: pooled @ Wo + bo ----------------
__global__ __launch_bounds__(256) void outproj_kernel(
    const float* __restrict__ mpart, const float* __restrict__ Wo,
    const float* __restrict__ bo, float* __restrict__ out) {
  int b = blockIdx.x, tid = threadIdx.x;
  __shared__ float pooled[256];
  float m = -__builtin_inff();
  for (int c = 0; c < 64; ++c) m = fmaxf(m, mpart[(b*64 + c)*256 + tid]);
  pooled[tid] = m;
  __syncthreads();
  float acc = bo[tid];
  for (int d = 0; d < 256; ++d) acc += pooled[d] * Wo[d*256 + tid];
  out[b*256 + tid] = acc;
}

// ---------------- host ----------------
extern "C" void kernel_launch(void* const* d_in, const int* in_sizes, int n_in,
                              void* d_out, int out_size, void* d_ws, size_t ws_size,
                              hipStream_t stream) {
  const float* x     = (const float*)d_in[0];
  const float* amask = (const float*)d_in[1];
  const float* Wq    = (const float*)d_in[2];
  const float* bq    = (const float*)d_in[3];
  const float* Wk    = (const float*)d_in[4];
  const float* bk    = (const float*)d_in[5];
  const float* W1f   = (const float*)d_in[8];
  const float* b1f   = (const float*)d_in[9];
  const float* W2f   = (const float*)d_in[10];
  const float* b2fp  = (const float*)d_in[11];
  const float* ln_g  = (const float*)d_in[12];
  const float* ln_b  = (const float*)d_in[13];
  const float* Whh   = (const float*)d_in[14];
  const float* b_ih  = (const float*)d_in[15];
  const float* b_hh  = (const float*)d_in[16];
  const float* Wp    = (const float*)d_in[17];
  const float* bp    = (const float*)d_in[18];
  const float* opW1  = (const float*)d_in[19];
  const float* opb1  = (const float*)d_in[20];
  const float* opW2  = (const float*)d_in[21];
  const float* opb2  = (const float*)d_in[22];
  const float* Wo    = (const float*)d_in[23];
  const float* bo    = (const float*)d_in[24];
  (void)in_sizes; (void)n_in; (void)out_size; (void)ws_size;

  // workspace layout (liveness-overlapped; peak ~88 MB)
  char* ws = (char*)d_ws;
  float*          q      = (float*)(ws + 0);                  // 2MB   } dead after refine8
  float*          kk     = (float*)(ws + 2097152);            // 2MB   }
  unsigned short* qbf    = (unsigned short*)(ws + 4194304);   // 1MB   }
  unsigned short* kbf    = (unsigned short*)(ws + 5242880);   // 1MB   }
  int*            candi  = (int*)(ws + 6291456);              // 8MB   }
  float*          candv  = (float*)(ws + 14680064);           // 8MB   }
  unsigned short* G1     = (unsigned short*)(ws + 0);         // 16MB overlays [0,16M) after refine8
  unsigned short* rmb    = (unsigned short*)(ws + 23068672);  // 8MB (residual; dead after gemm64_ffn2)
  float*          preLN  = (float*)(ws + 33554432);           // 16MB at [32M,48M)
  unsigned short* G1all  = (unsigned short*)(ws + 0);         // 64MB overlays [0,64M) at gemm64_opA
  unsigned short* h      = (unsigned short*)(ws + 67108864);  // 8MB, live through gemm64_opA
  unsigned short* W1ft   = (unsigned short*)(ws + 75497472);
  unsigned short* W2ft   = (unsigned short*)(ws + 75759616);
  unsigned short* opW1t  = (unsigned short*)(ws + 76021760);
  unsigned short* opW2t  = (unsigned short*)(ws + 77070336);
  unsigned int*   Whhp   = (unsigned int*)(ws + 78118912);    // 384KB
  float*          hpart  = (float*)(ws + 78512128);           // 256KB
  float*          wv     = (float*)(ws + 78774272);
  float*          wb2    = (float*)(ws + 78778368);
  float*          mpart  = (float*)(ws + 78782464);           // 256KB
  unsigned short* fusedB = (unsigned short*)(ws + 79044608);  // 8MB -> ends 87433216
  int*            sel    = (int*)(ws + 87433216);             // 256KB

  prep_weights<<<5504, 256, 0, stream>>>(W1f, W2f, opW1, opW2, Whh, W1ft, W2ft, opW1t, opW2t, Whhp);
  qk_proj<<<4096, 256, 0, stream>>>(x, Wq, bq, Wk, bk, q, kk, qbf, kbf);
  sim_scan<<<dim3(TT/64, NSC, BB), 256, 0, stream>>>(qbf, kbf, amask, candi, candv);
  refine8<<<MROWS/8, 256, 0, stream>>>(candi, candv, q, kk, amask, sel);
  gather_mean<<<MROWS/4, 256, 0, stream>>>(sel, x, rmb);
  gemm64_gelu<<<dim3(256, 4), 256, 0, stream>>>(rmb, W1ft, 512, 256, b1f, G1);
  gemm64_ffn2<<<dim3(256, 2), 256, 0, stream>>>(G1, W2ft, 256, 512, b2fp, rmb, preLN);
  ln_kernel<<<4096, 256, 0, stream>>>(preLN, ln_g, ln_b, h);
  hsum_kernel<<<dim3(64, BB), 256, 0, stream>>>(h, hpart);
  gru_kernel<<<4, 1024, 0, stream>>>(hpart, Whhp, b_ih, b_hh, Wp, bp, opb2, wv, wb2);
  gemm64_opA<<<dim3(256, 16), 256, 0, stream>>>(h, opW1t, 2048, 256, opb1, wv, G1all);
  gemm64_bf16<<<dim3(256, 2), 256, 0, stream>>>(G1all, opW2t, 256, 2048, wb2, fusedB);
  maxpool_kernel<<<dim3(64, BB), 256, 0, stream>>>(fusedB, mpart);
  outproj_kernel<<<4, 256, 0, stream>>>(mpart, Wo, bo, (float*)d_out);
}

// Round 24
// 267.560 us; speedup vs baseline: 1.0047x; 1.0047x over previous
//
#include <hip/hip_runtime.h>

// ---------------- constants ----------------
#define BB 4
#define TT 4096
#define DD 256
#define KQ 32
#define TOPK 4
#define NV 8
#define NL 4
#define MROWS (BB*TT)   // 16384
#define NSC 16          // s-chunk blocks in sim_scan
#define SSPAN 256       // s-rows per sim_scan block
#define NCAND (NSC*16)  // 256 candidates per row

typedef __attribute__((ext_vector_type(8))) __bf16 bf16x8;
typedef __attribute__((ext_vector_type(4))) float  f32x4;

__device__ __forceinline__ unsigned short f2bf(float f) {
  union { float f; unsigned u; } un; un.f = f;
  unsigned r = un.u + 0x7fffu + ((un.u >> 16) & 1u);
  return (unsigned short)(r >> 16);
}
__device__ __forceinline__ float b2f(unsigned short s) {
  union { unsigned u; float f; } un; un.u = ((unsigned)s) << 16;
  return un.f;
}
// async global->LDS 16B: dest is wave-uniform base (+lane*16 by HW), src per-lane
__device__ __forceinline__ void gload16(const unsigned short* g, unsigned short* l) {
  __builtin_amdgcn_global_load_lds((const __attribute__((address_space(1))) void*)(g),
                                   (__attribute__((address_space(3))) void*)(l), 16, 0, 0);
}

// keep top-4 (desc) with first-seen-wins on ties
__device__ __forceinline__ void ins4(float val, int s, float v[4], int id[4]) {
  if (val <= v[3]) return;
  v[3] = val; id[3] = s;
  #pragma unroll
  for (int j = 3; j > 0; --j) {
    if (v[j] > v[j-1]) {
      float tv = v[j]; v[j] = v[j-1]; v[j-1] = tv;
      int   ti = id[j]; id[j] = id[j-1]; id[j-1] = ti;
    }
  }
}

// ---------------- weight prep: transpose + bf16 convert ----------------
__global__ __launch_bounds__(256) void prep_weights(
    const float* __restrict__ W1f, const float* __restrict__ W2f,
    const float* __restrict__ opW1, const float* __restrict__ opW2,
    const float* __restrict__ Whh,
    unsigned short* __restrict__ W1ft, unsigned short* __restrict__ W2ft,
    unsigned short* __restrict__ opW1t, unsigned short* __restrict__ opW2t,
    unsigned int* __restrict__ Whhp) {
  int idx = blockIdx.x * 256 + threadIdx.x;
  if (idx < 131072) { int n = idx >> 8, d = idx & 255; W1ft[idx] = f2bf(W1f[d*512 + n]); return; }
  idx -= 131072;
  if (idx < 131072) { int n = idx >> 9, d = idx & 511; W2ft[idx] = f2bf(W2f[d*256 + n]); return; }
  idx -= 131072;
  if (idx < 524288) { int np = idx >> 8, d = idx & 255; int v = np >> 8, e = np & 255;
                      opW1t[idx] = f2bf(opW1[v*65536 + d*256 + e]); return; }
  idx -= 524288;
  if (idx < 524288) { int n = idx >> 11, kp = idx & 2047; int v = kp >> 8, k2 = kp & 255;
                      opW2t[idx] = f2bf(opW2[v*65536 + k2*256 + n]); return; }
  idx -= 524288;
  if (idx < 98304) {
    int dp = idx / 768, j = idx - dp*768;
    unsigned lo = f2bf(Whh[j*256 + 2*dp]);
    unsigned hi = f2bf(Whh[j*256 + 2*dp + 1]);
    Whhp[idx] = lo | (hi << 16);
  }
}

// ---------------- q/k projection (fp32 + bf16 copies) ----------------
__global__ __launch_bounds__(256) void qk_proj(
    const float* __restrict__ x, const float* __restrict__ Wq, const float* __restrict__ bq,
    const float* __restrict__ Wk, const float* __restrict__ bk,
    float* __restrict__ q, float* __restrict__ kk,
    unsigned short* __restrict__ qbf, unsigned short* __restrict__ kbf) {
  __shared__ float xs[1024];
  int tid = threadIdx.x;
  *(float4*)&xs[tid*4] = *(const float4*)&x[(size_t)blockIdx.x*1024 + tid*4];
  __syncthreads();
  int row = blockIdx.x*4 + (tid >> 6);
  int j = tid & 63;
  int jj = j & 31;
  const float* W = (j < 32) ? Wq : Wk;
  const float* xr = &xs[(tid >> 6) * 256];
  float acc = 0.f;
  #pragma unroll 8
  for (int d = 0; d < 256; ++d) acc += xr[d] * W[d*32 + jj];
  acc += (j < 32) ? bq[jj] : bk[jj];
  float* out = (j < 32) ? q : kk;
  unsigned short* outb = (j < 32) ? qbf : kbf;
  out[(size_t)row*32 + jj] = acc;
  outb[(size_t)row*32 + jj] = f2bf(acc);
}

// ---------------- sim scan via MFMA (per-lane top-4 + values) ----------------
// SSPAN=256: kfr 16KB -> ~8 blocks/CU
__global__ __launch_bounds__(256) void sim_scan(
    const unsigned short* __restrict__ qbf, const unsigned short* __restrict__ kbf,
    const float* __restrict__ mask, int* __restrict__ candi, float* __restrict__ candvv) {
  int b = blockIdx.z, sc = blockIdx.y;
  int q0 = blockIdx.x * 64;
  int tid = threadIdx.x;
  int w = tid >> 6, lane = tid & 63;
  int l15 = lane & 15, lhi = lane >> 4;

  __shared__ unsigned short kfr[SSPAN*32];  // 16KB, fragment-ordered
  __shared__ float ms[SSPAN];
  __shared__ int mflag;

  int qrow = q0 + w*16 + l15;
  bf16x8 qf = *(const bf16x8*)&qbf[((size_t)b*TT + qrow)*32 + lhi*8];
  float mrow = mask[b*TT + qrow];

  float vtop[4]; int itop[4];
  #pragma unroll
  for (int r = 0; r < 4; ++r) { vtop[r] = -__builtin_inff(); itop[r] = 0; }

  int s0 = sc * SSPAN;
  if (tid == 0) mflag = 0;
  __syncthreads();
  int anyzero = 0;
  {
    int s = tid;
    const unsigned short* src = &kbf[((size_t)b*TT + s0 + s)*32];
    uint4 d0 = *(const uint4*)(src);
    uint4 d1 = *(const uint4*)(src + 8);
    uint4 d2 = *(const uint4*)(src + 16);
    uint4 d3 = *(const uint4*)(src + 24);
    int fb = (s >> 4)*512 + (s & 15)*8;
    *(uint4*)&kfr[fb +   0] = d0;
    *(uint4*)&kfr[fb + 128] = d1;
    *(uint4*)&kfr[fb + 256] = d2;
    *(uint4*)&kfr[fb + 384] = d3;
    float mv = mask[b*TT + s0 + s];
    ms[s] = mv;
    if (mv == 0.f) anyzero = 1;
  }
  if (anyzero) mflag = 1;
  __syncthreads();
  bool useMask = (mflag != 0) || (mrow == 0.f);
  f32x4 z = {0.f, 0.f, 0.f, 0.f};
  for (int sf = 0; sf < SSPAN/16; sf += 2) {
    bf16x8 a0 = *(const bf16x8*)&kfr[(sf+0)*512 + lane*8];
    bf16x8 a1 = *(const bf16x8*)&kfr[(sf+1)*512 + lane*8];
    f32x4 c0 = __builtin_amdgcn_mfma_f32_16x16x32_bf16(a0, qf, z, 0, 0, 0);
    f32x4 c1 = __builtin_amdgcn_mfma_f32_16x16x32_bf16(a1, qf, z, 0, 0, 0);
    int sb0 = s0 + (sf+0)*16 + lhi*4;
    int sb1 = s0 + (sf+1)*16 + lhi*4;
    #pragma unroll
    for (int r = 0; r < 4; ++r) {
      float v0 = c0[r], v1 = c1[r];
      if (useMask) {
        if (mrow * ms[(sf+0)*16 + lhi*4 + r] == 0.f) v0 = -1e9f;
        if (mrow * ms[(sf+1)*16 + lhi*4 + r] == 0.f) v1 = -1e9f;
      }
      ins4(v0, sb0 + r, vtop, itop);
      ins4(v1, sb1 + r, vtop, itop);
    }
  }
  size_t base = ((size_t)(b*TT + qrow))*NCAND + sc*16 + lhi*4;
  #pragma unroll
  for (int r = 0; r < 4; ++r) { candi[base + r] = itop[r]; candvv[base + r] = vtop[r]; }
}

// ---------------- preselect top-8 by bf16 value + exact fp32 rank of 8 ----------------
// NCAND=256: 8 candidates per lane
__global__ __launch_bounds__(256) void refine8(
    const int* __restrict__ candi, const float* __restrict__ candv,
    const float* __restrict__ q, const float* __restrict__ kk,
    const float* __restrict__ mask, int* __restrict__ sel) {
  int tid = threadIdx.x;
  int g = tid >> 5, j = tid & 31;
  int row = blockIdx.x*8 + g;
  int b = row >> 12;
  float v[8]; int id[8];
  const float* cvp = &candv[(size_t)row*NCAND];
  const int*   cip = &candi[(size_t)row*NCAND];
  #pragma unroll
  for (int k2 = 0; k2 < 8; ++k2) { v[k2] = cvp[j + k2*32]; id[k2] = cip[j + k2*32]; }
  int c8[8];
  #pragma unroll
  for (int r = 0; r < 8; ++r) {
    float bv = v[0]; int bi = id[0];
    #pragma unroll
    for (int k2 = 1; k2 < 8; ++k2)
      if (v[k2] > bv || (v[k2] == bv && id[k2] < bi)) { bv = v[k2]; bi = id[k2]; }
    #pragma unroll
    for (int o = 16; o > 0; o >>= 1) {
      float ov = __shfl_xor(bv, o, 32);
      int   oi = __shfl_xor(bi, o, 32);
      if (ov > bv || (ov == bv && oi < bi)) { bv = ov; bi = oi; }
    }
    c8[r] = bi;
    #pragma unroll
    for (int k2 = 0; k2 < 8; ++k2) if (id[k2] == bi) v[k2] = -__builtin_inff();
  }
  // exact fp32 dots
  int ca = c8[j >> 2];
  int seg = (j & 3) * 8;
  const float* kp = &kk[((size_t)(b << 12) + ca)*32 + seg];
  const float* qp = &q[(size_t)row*32 + seg];
  float pd = 0.f;
  #pragma unroll
  for (int t = 0; t < 8; t += 4) {
    float4 kv = *(const float4*)&kp[t];
    float4 qv = *(const float4*)&qp[t];
    pd += kv.x*qv.x + kv.y*qv.y + kv.z*qv.z + kv.w*qv.w;
  }
  pd += __shfl_xor(pd, 1, 32);
  pd += __shfl_xor(pd, 2, 32);
  if (mask[row] * mask[(b << 12) + ca] == 0.f) pd = -1e9f;
  float dv[8];
  #pragma unroll
  for (int c = 0; c < 8; ++c) dv[c] = __shfl(pd, c*4, 32);
  if (j == 0) {
    int s0 = -1, s1 = -1, s2 = -1, s3 = -1;
    int4 o4;
    #pragma unroll
    for (int r = 0; r < 4; ++r) {
      float bv = -__builtin_inff(); int bi = 0x7fffffff;
      #pragma unroll
      for (int c = 0; c < 8; ++c) {
        int ii = c8[c]; float vv = dv[c];
        if (ii == s0 || ii == s1 || ii == s2 || ii == s3) continue;
        if (vv > bv || (vv == bv && ii < bi)) { bv = vv; bi = ii; }
      }
      if (r == 0) { o4.x = bi; s0 = bi; }
      else if (r == 1) { o4.y = bi; s1 = bi; }
      else if (r == 2) { o4.z = bi; s2 = bi; }
      else { o4.w = bi; s3 = bi; }
    }
    *(int4*)&sel[(size_t)row*4] = o4;
  }
}

// ---------------- gather + routed_mean (pure streaming) ----------------
__global__ __launch_bounds__(256) void gather_mean(
    const int* __restrict__ sel, const float* __restrict__ x,
    unsigned short* __restrict__ rmb) {
  int tid = threadIdx.x;
  int row = blockIdx.x*4 + (tid >> 6);
  int lane = tid & 63;
  int b = row >> 12;
  int4 s = *(const int4*)&sel[(size_t)row*4];
  const float* xb = &x[(size_t)b*TT*DD];
  float4 a  = *(const float4*)&xb[(size_t)s.x*DD + lane*4];
  float4 bb = *(const float4*)&xb[(size_t)s.y*DD + lane*4];
  float4 cc = *(const float4*)&xb[(size_t)s.z*DD + lane*4];
  float4 e  = *(const float4*)&xb[(size_t)s.w*DD + lane*4];
  ushort4 o;
  o.x = f2bf((a.x + bb.x + cc.x + e.x)*0.25f);
  o.y = f2bf((a.y + bb.y + cc.y + e.y)*0.25f);
  o.z = f2bf((a.z + bb.z + cc.z + e.z)*0.25f);
  o.w = f2bf((a.w + bb.w + cc.w + e.w)*0.25f);
  *(ushort4*)&rmb[(size_t)row*DD + lane*4] = o;
}

// ---------------- bf16 MFMA GEMM, 64x128 tile (long-K gemm<3>), gload_lds staging ----------------
__global__ __launch_bounds__(256) void gemm64_bf16(
    const unsigned short* __restrict__ A, const unsigned short* __restrict__ Bt,
    int Ndim, int Kdim,
    const float* __restrict__ auxf, unsigned short* __restrict__ outB) {
  __shared__ unsigned short SMEM[64*192 + 64];  // As 4096 + Bs 8192 staging; CT 64x132
  unsigned short* As = SMEM;
  unsigned short* Bs = SMEM + 64*64;
  int tid = threadIdx.x;
  int lane = tid & 63, wn = tid >> 6;
  int l16 = lane & 15, lhi = lane >> 4;
  int m0 = blockIdx.x * 64, n0 = blockIdx.y * 128;
  f32x4 acc[4][2] = {};
  for (int kt = 0; kt < Kdim; kt += 64) {
    __syncthreads();
    #pragma unroll
    for (int i = 0; i < 2; ++i) {
      int L0 = i*256 + wn*64;
      int L  = L0 + lane;
      int r = L >> 3;
      int csrc = ((lane & 7) ^ (r & 7)) * 8;
      gload16(A + (size_t)(m0 + r)*Kdim + kt + csrc, &As[L0*8]);
    }
    #pragma unroll
    for (int i = 0; i < 4; ++i) {
      int L0 = i*256 + wn*64;
      int L  = L0 + lane;
      int r = L >> 3;
      int csrc = ((lane & 7) ^ (r & 7)) * 8;
      gload16(Bt + (size_t)(n0 + r)*Kdim + kt + csrc, &Bs[L0*8]);
    }
    __syncthreads();
    #pragma unroll
    for (int ks = 0; ks < 2; ++ks) {
      bf16x8 af[4], bfr[2];
      int kc = ks*4 + lhi;
      #pragma unroll
      for (int f = 0; f < 4; ++f) {
        int ra = f*16 + l16;
        af[f] = *(const bf16x8*)&As[ra*64 + ((kc ^ (ra & 7)))*8];
      }
      #pragma unroll
      for (int f = 0; f < 2; ++f) {
        int rb = wn*32 + f*16 + l16;
        bfr[f] = *(const bf16x8*)&Bs[rb*64 + ((kc ^ (rb & 7)))*8];
      }
      #pragma unroll
      for (int mf = 0; mf < 4; ++mf)
        #pragma unroll
        for (int nf = 0; nf < 2; ++nf)
          acc[mf][nf] = __builtin_amdgcn_mfma_f32_16x16x32_bf16(af[mf], bfr[nf], acc[mf][nf], 0, 0, 0);
    }
  }
  __syncthreads();   // reuse SMEM as CT[64][132]
  #pragma unroll
  for (int mf = 0; mf < 4; ++mf) {
    #pragma unroll
    for (int nf = 0; nf < 2; ++nf) {
      #pragma unroll
      for (int r = 0; r < 4; ++r) {
        int lrow = mf*16 + lhi*4 + r;
        int lcol = wn*32 + nf*16 + l16;
        float v = acc[mf][nf][r] + auxf[((m0 + lrow) >> 12)*256 + n0 + lcol];
        SMEM[lrow*132 + lcol] = f2bf(v);
      }
    }
  }
  __syncthreads();
  #pragma unroll
  for (int i = 0; i < 4; ++i) {
    int idx = i*256 + tid;
    int lrow = idx >> 4, co = (idx & 15)*8;
    *(uint4*)&outB[(size_t)(m0 + lrow)*Ndim + n0 + co] = *(const uint4*)&SMEM[lrow*132 + co];
  }
}

// ---------------- gemm64 variant for op GEMM-A: relu(acc + opb1)*w -> bf16, CT-retile ----------------
__global__ __launch_bounds__(256) void gemm64_opA(
    const unsigned short* __restrict__ A, const unsigned short* __restrict__ Bt,
    int Ndim, int Kdim,
    const float* __restrict__ bias, const float* __restrict__ wv,
    unsigned short* __restrict__ outB) {
  __shared__ unsigned short SMEM[64*192 + 64];
  unsigned short* As = SMEM;
  unsigned short* Bs = SMEM + 64*64;
  int tid = threadIdx.x;
  int lane = tid & 63, wn = tid >> 6;
  int l16 = lane & 15, lhi = lane >> 4;
  int m0 = blockIdx.x * 64, n0 = blockIdx.y * 128;
  f32x4 acc[4][2] = {};
  for (int kt = 0; kt < Kdim; kt += 64) {
    __syncthreads();
    #pragma unroll
    for (int i = 0; i < 2; ++i) {
      int L0 = i*256 + wn*64;
      int L  = L0 + lane;
      int r = L >> 3;
      int csrc = ((lane & 7) ^ (r & 7)) * 8;
      gload16(A + (size_t)(m0 + r)*Kdim + kt + csrc, &As[L0*8]);
    }
    #pragma unroll
    for (int i = 0; i < 4; ++i) {
      int L0 = i*256 + wn*64;
      int L  = L0 + lane;
      int r = L >> 3;
      int csrc = ((lane & 7) ^ (r & 7)) * 8;
      gload16(Bt + (size_t)(n0 + r)*Kdim + kt + csrc, &Bs[L0*8]);
    }
    __syncthreads();
    #pragma unroll
    for (int ks = 0; ks < 2; ++ks) {
      bf16x8 af[4], bfr[2];
      int kc = ks*4 + lhi;
      #pragma unroll
      for (int f = 0; f < 4; ++f) {
        int ra = f*16 + l16;
        af[f] = *(const bf16x8*)&As[ra*64 + ((kc ^ (ra & 7)))*8];
      }
      #pragma unroll
      for (int f = 0; f < 2; ++f) {
        int rb = wn*32 + f*16 + l16;
        bfr[f] = *(const bf16x8*)&Bs[rb*64 + ((kc ^ (rb & 7)))*8];
      }
      #pragma unroll
      for (int mf = 0; mf < 4; ++mf)
        #pragma unroll
        for (int nf = 0; nf < 2; ++nf)
          acc[mf][nf] = __builtin_amdgcn_mfma_f32_16x16x32_bf16(af[mf], bfr[nf], acc[mf][nf], 0, 0, 0);
    }
  }
  __syncthreads();   // reuse SMEM as CT[64][132]
  int bq = (m0 >> 12);                    // batch index (rows/4096)
  #pragma unroll
  for (int mf = 0; mf < 4; ++mf) {
    #pragma unroll
    for (int nf = 0; nf < 2; ++nf) {
      int col = n0 + wn*32 + nf*16 + l16;
      float bv = bias[col];
      float wvv = wv[bq*8 + (col >> 8)];
      #pragma unroll
      for (int r = 0; r < 4; ++r) {
        int lrow = mf*16 + lhi*4 + r;
        int lcol = wn*32 + nf*16 + l16;
        float v = acc[mf][nf][r] + bv;
        v = fmaxf(v, 0.0f) * wvv;
        SMEM[lrow*132 + lcol] = f2bf(v);
      }
    }
  }
  __syncthreads();
  #pragma unroll
  for (int i = 0; i < 4; ++i) {
    int idx = i*256 + tid;
    int lrow = idx >> 4, co = (idx & 15)*8;
    *(uint4*)&outB[(size_t)(m0 + lrow)*Ndim + n0 + co] = *(const uint4*)&SMEM[lrow*132 + co];
  }
}

// ---------------- gemm64 variant for FFN1: gelu(acc + bias) -> bf16, CT-retile ----------------
__global__ __launch_bounds__(256) void gemm64_gelu(
    const unsigned short* __restrict__ A, const unsigned short* __restrict__ Bt,
    int Ndim, int Kdim,
    const float* __restrict__ bias, unsigned short* __restrict__ outB) {
  __shared__ unsigned short SMEM[64*192 + 64];
  unsigned short* As = SMEM;
  unsigned short* Bs = SMEM + 64*64;
  int tid = threadIdx.x;
  int lane = tid & 63, wn = tid >> 6;
  int l16 = lane & 15, lhi = lane >> 4;
  int m0 = blockIdx.x * 64, n0 = blockIdx.y * 128;
  f32x4 acc[4][2] = {};
  for (int kt = 0; kt < Kdim; kt += 64) {
    __syncthreads();
    #pragma unroll
    for (int i = 0; i < 2; ++i) {
      int L0 = i*256 + wn*64;
      int L  = L0 + lane;
      int r = L >> 3;
      int csrc = ((lane & 7) ^ (r & 7)) * 8;
      gload16(A + (size_t)(m0 + r)*Kdim + kt + csrc, &As[L0*8]);
    }
    #pragma unroll
    for (int i = 0; i < 4; ++i) {
      int L0 = i*256 + wn*64;
      int L  = L0 + lane;
      int r = L >> 3;
      int csrc = ((lane & 7) ^ (r & 7)) * 8;
      gload16(Bt + (size_t)(n0 + r)*Kdim + kt + csrc, &Bs[L0*8]);
    }
    __syncthreads();
    #pragma unroll
    for (int ks = 0; ks < 2; ++ks) {
      bf16x8 af[4], bfr[2];
      int kc = ks*4 + lhi;
      #pragma unroll
      for (int f = 0; f < 4; ++f) {
        int ra = f*16 + l16;
        af[f] = *(const bf16x8*)&As[ra*64 + ((kc ^ (ra & 7)))*8];
      }
      #pragma unroll
      for (int f = 0; f < 2; ++f) {
        int rb = wn*32 + f*16 + l16;
        bfr[f] = *(const bf16x8*)&Bs[rb*64 + ((kc ^ (rb & 7)))*8];
      }
      #pragma unroll
      for (int mf = 0; mf < 4; ++mf)
        #pragma unroll
        for (int nf = 0; nf < 2; ++nf)
          acc[mf][nf] = __builtin_amdgcn_mfma_f32_16x16x32_bf16(af[mf], bfr[nf], acc[mf][nf], 0, 0, 0);
    }
  }
  __syncthreads();   // reuse SMEM as CT[64][132]
  #pragma unroll
  for (int mf = 0; mf < 4; ++mf) {
    #pragma unroll
    for (int nf = 0; nf < 2; ++nf) {
      int col = n0 + wn*32 + nf*16 + l16;
      float bv = bias[col];
      #pragma unroll
      for (int r = 0; r < 4; ++r) {
        int lrow = mf*16 + lhi*4 + r;
        int lcol = wn*32 + nf*16 + l16;
        float v = acc[mf][nf][r] + bv;
        v = 0.5f * v * (1.0f + erff(v * 0.70710678118654752f));
        SMEM[lrow*132 + lcol] = f2bf(v);
      }
    }
  }
  __syncthreads();
  #pragma unroll
  for (int i = 0; i < 4; ++i) {
    int idx = i*256 + tid;
    int lrow = idx >> 4, co = (idx & 15)*8;
    *(uint4*)&outB[(size_t)(m0 + lrow)*Ndim + n0 + co] = *(const uint4*)&SMEM[lrow*132 + co];
  }
}

// ---------------- gemm64 variant for FFN2: f32 preLN = acc + bias + residual ----------------
__global__ __launch_bounds__(256) void gemm64_ffn2(
    const unsigned short* __restrict__ A, const unsigned short* __restrict__ Bt,
    int Ndim, int Kdim,
    const float* __restrict__ bias, const unsigned short* __restrict__ resB,
    float* __restrict__ outF) {
  __shared__ unsigned short SMEM[64*192 + 64];
  unsigned short* As = SMEM;
  unsigned short* Bs = SMEM + 64*64;
  int tid = threadIdx.x;
  int lane = tid & 63, wn = tid >> 6;
  int l16 = lane & 15, lhi = lane >> 4;
  int m0 = blockIdx.x * 64, n0 = blockIdx.y * 128;
  f32x4 acc[4][2] = {};
  for (int kt = 0; kt < Kdim; kt += 64) {
    __syncthreads();
    #pragma unroll
    for (int i = 0; i < 2; ++i) {
      int L0 = i*256 + wn*64;
      int L  = L0 + lane;
      int r = L >> 3;
      int csrc = ((lane & 7) ^ (r & 7)) * 8;
      gload16(A + (size_t)(m0 + r)*Kdim + kt + csrc, &As[L0*8]);
    }
    #pragma unroll
    for (int i = 0; i < 4; ++i) {
      int L0 = i*256 + wn*64;
      int L  = L0 + lane;
      int r = L >> 3;
      int csrc = ((lane & 7) ^ (r & 7)) * 8;
      gload16(Bt + (size_t)(n0 + r)*Kdim + kt + csrc, &Bs[L0*8]);
    }
    __syncthreads();
    #pragma unroll
    for (int ks = 0; ks < 2; ++ks) {
      bf16x8 af[4], bfr[2];
      int kc = ks*4 + lhi;
      #pragma unroll
      for (int f = 0; f < 4; ++f) {
        int ra = f*16 + l16;
        af[f] = *(const bf16x8*)&As[ra*64 + ((kc ^ (ra & 7)))*8];
      }
      #pragma unroll
      for (int f = 0; f < 2; ++f) {
        int rb = wn*32 + f*16 + l16;
        bfr[f] = *(const bf16x8*)&Bs[rb*64 + ((kc ^ (rb & 7)))*8];
      }
      #pragma unroll
      for (int mf = 0; mf < 4; ++mf)
        #pragma unroll
        for (int nf = 0; nf < 2; ++nf)
          acc[mf][nf] = __builtin_amdgcn_mfma_f32_16x16x32_bf16(af[mf], bfr[nf], acc[mf][nf], 0, 0, 0);
    }
  }
  #pragma unroll
  for (int mf = 0; mf < 4; ++mf) {
    #pragma unroll
    for (int nf = 0; nf < 2; ++nf) {
      #pragma unroll
      for (int r = 0; r < 4; ++r) {
        int row = m0 + mf*16 + lhi*4 + r;
        int col = n0 + wn*32 + nf*16 + l16;
        float v = acc[mf][nf][r] + bias[col] + b2f(resB[(size_t)row*Ndim + col]);
        outF[(size_t)row*Ndim + col] = v;
      }
    }
  }
}

// ---------------- LayerNorm: one wave per row ----------------
__global__ __launch_bounds__(256) void ln_kernel(
    const float* __restrict__ preLN, const float* __restrict__ g,
    const float* __restrict__ bta, unsigned short* __restrict__ h) {
  int tid = threadIdx.x;
  int lane = tid & 63;
  int row = blockIdx.x*4 + (tid >> 6);
  float4 v = *(const float4*)&preLN[(size_t)row*256 + lane*4];
  float s = v.x + v.y + v.z + v.w;
  #pragma unroll
  for (int o = 32; o > 0; o >>= 1) s += __shfl_xor(s, o);
  float mu = s * (1.0f/256.0f);
  float4 d; d.x = v.x-mu; d.y = v.y-mu; d.z = v.z-mu; d.w = v.w-mu;
  float s2 = d.x*d.x + d.y*d.y + d.z*d.z + d.w*d.w;
  #pragma unroll
  for (int o = 32; o > 0; o >>= 1) s2 += __shfl_xor(s2, o);
  float rstd = rsqrtf(s2 * (1.0f/256.0f) + 1e-5f);
  float4 gv = *(const float4*)&g[lane*4];
  float4 bv = *(const float4*)&bta[lane*4];
  ushort4 o;
  o.x = f2bf(d.x*rstd*gv.x + bv.x);
  o.y = f2bf(d.y*rstd*gv.y + bv.y);
  o.z = f2bf(d.z*rstd*gv.z + bv.z);
  o.w = f2bf(d.w*rstd*gv.w + bv.w);
  *(ushort4*)&h[(size_t)row*256 + lane*4] = o;
}

// ---------------- partial column-sum of h (64-row chunks) ----------------
__global__ __launch_bounds__(256) void hsum_kernel(const unsigned short* __restrict__ h, float* __restrict__ hpart) {
  int c = blockIdx.x, b = blockIdx.y, d = threadIdx.x;
  const unsigned short* hp = &h[((size_t)(b*TT + c*64))*256 + d];
  float s = 0.f;
  #pragma unroll 8
  for (int i = 0; i < 64; ++i) s += b2f(hp[i*256]);
  hpart[(b*64 + c)*256 + d] = s;
}

// ---------------- GRU v5: 1024 threads (16 waves), one gate output per thread ----------------
__global__ __launch_bounds__(1024) void gru_kernel(
    const float* __restrict__ hpart, const unsigned int* __restrict__ Whhp,
    const float* __restrict__ b_ih, const float* __restrict__ b_hh,
    const float* __restrict__ Wp, const float* __restrict__ bp,
    const float* __restrict__ opb2, float* __restrict__ w, float* __restrict__ wb2) {
  int b = blockIdx.x, tid = threadIdx.x;
  __shared__ float hs[256];
  __shared__ float gsh[768];
  __shared__ float wps[2048];
  __shared__ float lgpart[256];
  __shared__ float lg[8];
  __shared__ float wacc[8];
  if (tid < 256) {
    float s = 0.f;
    #pragma unroll
    for (int c = 0; c < 64; ++c) s += hpart[(b*64 + c)*256 + tid];
    hs[tid] = s * (1.0f/4096.0f);
  }
  wps[tid] = Wp[tid];
  wps[1024 + tid] = Wp[1024 + tid];
  if (tid < 8) wacc[tid] = 0.f;
  __syncthreads();
  for (int l = 0; l < NL; ++l) {
    if (tid < 768) {
      float acc = 0.f;
      #pragma unroll 16
      for (int dp = 0; dp < 128; ++dp) {
        unsigned w2 = Whhp[dp*768 + tid];
        acc += b2f((unsigned short)(w2 & 0xffff))*hs[2*dp]
             + b2f((unsigned short)(w2 >> 16))*hs[2*dp + 1];
      }
      gsh[tid] = acc;
    }
    __syncthreads();
    if (tid < 256) {
      float g0 = gsh[tid]       + b_hh[tid];
      float g1 = gsh[256 + tid] + b_hh[256 + tid];
      float g2 = gsh[512 + tid] + b_hh[512 + tid];
      float r = 1.f / (1.f + expf(-(b_ih[tid] + g0)));
      float z = 1.f / (1.f + expf(-(b_ih[256 + tid] + g1)));
      float n = tanhf(b_ih[512 + tid] + r * g2);
      gsh[tid] = (1.f - z) * n + z * hs[tid];
    }
    __syncthreads();
    if (tid < 256) hs[tid] = gsh[tid];
    __syncthreads();
    if (tid < 256) {
      int dp2 = tid >> 3;
      float acc = 0.f;
      #pragma unroll
      for (int k2 = 0; k2 < 8; ++k2) acc += hs[dp2 + 32*k2] * wps[tid + 256*k2];
      lgpart[tid] = acc;
    }
    __syncthreads();
    if (tid < 8) {
      float acc = bp[tid];
      #pragma unroll
      for (int j = 0; j < 32; ++j) acc += lgpart[j*8 + tid];
      lg[tid] = acc;
    }
    __syncthreads();
    if (tid == 0) {
      float mx = lg[0];
      #pragma unroll
      for (int i = 1; i < 8; ++i) mx = fmaxf(mx, lg[i]);
      float sm = 0.f; float e[8];
      #pragma unroll
      for (int i = 0; i < 8; ++i) { e[i] = expf(lg[i] - mx); sm += e[i]; }
      #pragma unroll
      for (int i = 0; i < 8; ++i) wacc[i] += e[i] / sm;
    }
    __syncthreads();
  }
  if (tid < 8) w[b*8 + tid] = wacc[tid] * 0.25f;
  if (tid < 256) {
    float acc = 0.f;
    #pragma unroll
    for (int v = 0; v < 8; ++v) acc += (wacc[v] * 0.25f) * opb2[v*256 + tid];
    wb2[b*256 + tid] = acc;
  }
}

// ---------------- max-pool partials (64-row chunks) ----------------
__global__ __launch_bounds__(256) void maxpool_kernel(const unsigned short* __restrict__ fusedB, float* __restrict__ mpart) {
  int c = blockIdx.x, b = blockIdx.y, d = threadIdx.x;
  const unsigned short* fp = &fusedB[((size_t)(b*TT + c*64))*256 + d];
  float m = -__builtin_inff();
  #pragma unroll 8
  for (int i = 0; i < 64; ++i) m = fmaxf(m, b2f(fp[i*256]));
  mpart[(b*64 + c)*256 + d] = m;
}

// ---------------- final: pooled @ Wo + bo ----------------
__global__ __launch_bounds__(256) void outproj_kernel(
    const float* __restrict__ mpart, const float* __restrict__ Wo,
    const float* __restrict__ bo, float* __restrict__ out) {
  int b = blockIdx.x, tid = threadIdx.x;
  __shared__ float pooled[256];
  float m = -__builtin_inff();
  for (int c = 0; c < 64; ++c) m = fmaxf(m, mpart[(b*64 + c)*256 + tid]);
  pooled[tid] = m;
  __syncthreads();
  float acc = bo[tid];
  for (int d = 0; d < 256; ++d) acc += pooled[d] * Wo[d*256 + tid];
  out[b*256 + tid] = acc;
}

// ---------------- host ----------------
extern "C" void kernel_launch(void* const* d_in, const int* in_sizes, int n_in,
                              void* d_out, int out_size, void* d_ws, size_t ws_size,
                              hipStream_t stream) {
  const float* x     = (const float*)d_in[0];
  const float* amask = (const float*)d_in[1];
  const float* Wq    = (const float*)d_in[2];
  const float* bq    = (const float*)d_in[3];
  const float* Wk    = (const float*)d_in[4];
  const float* bk    = (const float*)d_in[5];
  const float* W1f   = (const float*)d_in[8];
  const float* b1f   = (const float*)d_in[9];
  const float* W2f   = (const float*)d_in[10];
  const float* b2fp  = (const float*)d_in[11];
  const float* ln_g  = (const float*)d_in[12];
  const float* ln_b  = (const float*)d_in[13];
  const float* Whh   = (const float*)d_in[14];
  const float* b_ih  = (const float*)d_in[15];
  const float* b_hh  = (const float*)d_in[16];
  const float* Wp    = (const float*)d_in[17];
  const float* bp    = (const float*)d_in[18];
  const float* opW1  = (const float*)d_in[19];
  const float* opb1  = (const float*)d_in[20];
  const float* opW2  = (const float*)d_in[21];
  const float* opb2  = (const float*)d_in[22];
  const float* Wo    = (const float*)d_in[23];
  const float* bo    = (const float*)d_in[24];
  (void)in_sizes; (void)n_in; (void)out_size; (void)ws_size;

  // workspace layout (liveness-overlapped)
  char* ws = (char*)d_ws;
  float*          q      = (float*)(ws + 0);                  // 2MB   } dead after refine8
  float*          kk     = (float*)(ws + 2097152);            // 2MB   }
  unsigned short* qbf    = (unsigned short*)(ws + 4194304);   // 1MB   }
  unsigned short* kbf    = (unsigned short*)(ws + 5242880);   // 1MB   }
  int*            candi  = (int*)(ws + 6291456);              // 16MB  } ends 23068672
  float*          candv  = (float*)(ws + 23068672);           // 16MB  } ends 39845888
  unsigned short* G1     = (unsigned short*)(ws + 0);         // 16MB overlays [0,16M) after refine8
  unsigned short* rmb    = (unsigned short*)(ws + 39845888);  // 8MB (residual; dead after gemm64_ffn2)
  float*          preLN  = (float*)(ws + 48234496);           // 16MB -> ends 65011712
  unsigned short* G1all  = (unsigned short*)(ws + 0);         // 64MB overlays [0,64M) at gemm64_opA
  unsigned short* h      = (unsigned short*)(ws + 67108864);  // 8MB, live through gemm64_opA
  unsigned short* W1ft   = (unsigned short*)(ws + 75497472);
  unsigned short* W2ft   = (unsigned short*)(ws + 75759616);
  unsigned short* opW1t  = (unsigned short*)(ws + 76021760);
  unsigned short* opW2t  = (unsigned short*)(ws + 77070336);
  unsigned int*   Whhp   = (unsigned int*)(ws + 78118912);    // 384KB
  float*          hpart  = (float*)(ws + 78512128);           // 256KB
  float*          wv     = (float*)(ws + 78774272);
  float*          wb2    = (float*)(ws + 78778368);
  float*          mpart  = (float*)(ws + 78782464);           // 256KB
  unsigned short* fusedB = (unsigned short*)(ws + 79044608);  // 8MB -> ends 87433216
  int*            sel    = (int*)(ws + 87433216);             // 256KB

  prep_weights<<<5504, 256, 0, stream>>>(W1f, W2f, opW1, opW2, Whh, W1ft, W2ft, opW1t, opW2t, Whhp);
  qk_proj<<<4096, 256, 0, stream>>>(x, Wq, bq, Wk, bk, q, kk, qbf, kbf);
  sim_scan<<<dim3(TT/64, NSC, BB), 256, 0, stream>>>(qbf, kbf, amask, candi, candv);
  refine8<<<MROWS/8, 256, 0, stream>>>(candi, candv, q, kk, amask, sel);
  gather_mean<<<MROWS/4, 256, 0, stream>>>(sel, x, rmb);
  gemm64_gelu<<<dim3(256, 4), 256, 0, stream>>>(rmb, W1ft, 512, 256, b1f, G1);
  gemm64_ffn2<<<dim3(256, 2), 256, 0, stream>>>(G1, W2ft, 256, 512, b2fp, rmb, preLN);
  ln_kernel<<<4096, 256, 0, stream>>>(preLN, ln_g, ln_b, h);
  hsum_kernel<<<dim3(64, BB), 256, 0, stream>>>(h, hpart);
  gru_kernel<<<4, 1024, 0, stream>>>(hpart, Whhp, b_ih, b_hh, Wp, bp, opb2, wv, wb2);
  gemm64_opA<<<dim3(256, 16), 256, 0, stream>>>(h, opW1t, 2048, 256, opb1, wv, G1all);
  gemm64_bf16<<<dim3(256, 2), 256, 0, stream>>>(G1all, opW2t, 256, 2048, wb2, fusedB);
  maxpool_kernel<<<dim3(64, BB), 256, 0, stream>>>(fusedB, mpart);
  outproj_kernel<<<4, 256, 0, stream>>>(mpart, Wo, bo, (float*)d_out);
}